// Round 6
// baseline (169.959 us; speedup 1.0000x reference)
//
#include <hip/hip_runtime.h>
#include <hip/hip_bf16.h>

typedef __attribute__((ext_vector_type(4))) float f32x4;
typedef __attribute__((ext_vector_type(8))) short s16x8;
typedef unsigned int uint;
typedef unsigned short ushort;
typedef unsigned long long u64;

// N=8192, INP=512, OUT=256
// out = relu(D^-1/2 (binA+I) D^-1/2 (x@w)) @ lin_w^T + lin_b
// binA packed to bits via wave ballot (k-axis permuted by kappa); bf16 MFMA GEMMs.

__device__ inline ushort f2bf(float f) {
  union { float f; uint u; } v; v.f = f;
  uint r = (v.u + 0x7FFFu + ((v.u >> 16) & 1u)) >> 16;   // RNE
  return (ushort)r;
}
__device__ inline float bf2f(ushort h) { union { uint u; float f; } v; v.u = ((uint)h) << 16; return v.f; }
__device__ inline uint pack2(float a, float b) { return (uint)f2bf(a) | ((uint)f2bf(b) << 16); }
// ballot packing permutation: column j -> packed k position (within each 256-col block)
__device__ inline int kappa(int j) {
  return (j & ~255) | ((j & 3) << 6) | (((j >> 7) & 1) << 5) | ((j >> 2) & 31);
}

// ---------------- K1: ballot bit-pack, one row per wave, reg double-buffer ----
// grid 2048 x 256thr (4 waves = 4 rows/block). Row = 2048 float4; lane covers
// f4-index bt*256 + j*64 + lane; always >=4 loads in flight.
__global__ __launch_bounds__(256, 4) void k_pack(const float* __restrict__ adj,
                                                 const float* __restrict__ w,
                                                 const float* __restrict__ lw,
                                                 uint* __restrict__ bits,
                                                 float* __restrict__ dinv,
                                                 float* __restrict__ dk,
                                                 ushort* __restrict__ wT,
                                                 ushort* __restrict__ lwb) {
  const int t = threadIdx.x, lane = t & 63, wv = t >> 6;
  const int b = blockIdx.x;
  const int row = b * 4 + wv;
  const float4* src = (const float4*)(adj + (size_t)row * 8192) + lane;
  uint* dst = bits + (size_t)row * 256;
  float4 cur[4], nxt[4];
#pragma unroll
  for (int j = 0; j < 4; ++j) cur[j] = src[j * 64];
  int cnt = 0;
  for (int bt = 0; bt < 8; ++bt) {
    if (bt < 7) {
#pragma unroll
      for (int j = 0; j < 4; ++j) nxt[j] = src[(bt + 1) * 256 + j * 64];
    }
#pragma unroll
    for (int j = 0; j < 4; ++j) {
      u64 b0 = __ballot(cur[j].x > 0.5f), b1 = __ballot(cur[j].y > 0.5f);
      u64 b2 = __ballot(cur[j].z > 0.5f), b3 = __ballot(cur[j].w > 0.5f);
      cnt += __popcll(b0) + __popcll(b1) + __popcll(b2) + __popcll(b3);
      if (lane == 0) {
        uint4* d4 = (uint4*)(dst + (bt * 4 + j) * 8);
        d4[0] = make_uint4((uint)b0, (uint)(b0 >> 32), (uint)b1, (uint)(b1 >> 32));
        d4[1] = make_uint4((uint)b2, (uint)(b2 >> 32), (uint)b3, (uint)(b3 >> 32));
      }
    }
#pragma unroll
    for (int j = 0; j < 4; ++j) cur[j] = nxt[j];
  }
  if (lane == 0) {
    float d = rsqrtf((float)(cnt + 1));
    dinv[row] = d;
    dk[kappa(row)] = d;
  }
  // tiny preps: wT bf16 [n][k] (blocks 0..15), lwb bf16 copy of lin_w (blocks 16..23)
  if (b < 16) {
#pragma unroll
    for (int kk = 0; kk < 32; ++kk) {
      int k = b * 32 + kk;
      wT[(size_t)t * 512 + k] = f2bf(w[(size_t)k * 256 + t]);
    }
  } else if (b < 24) {
    const int b2 = b - 16;
    const float4* s = (const float4*)lw + b2 * 2048;
    uint2* d = (uint2*)lwb + b2 * 2048;
#pragma unroll
    for (int ii = 0; ii < 8; ++ii) {
      float4 v = s[ii * 256 + t];
      uint2 p; p.x = pack2(v.x, v.y); p.y = pack2(v.z, v.w);
      d[ii * 256 + t] = p;
    }
  }
}

// ---------------- K2: zT[n][k] = dk[k]*(x@w)[j(k)][n], bf16 MFMA --------------
// grid 256, 512 thr = 8 waves (2 mg x 4 ng); x slice preloaded to regs upfront.
__global__ __launch_bounds__(512) void k_xw(const float* __restrict__ x,
                                            const ushort* __restrict__ wT,
                                            const float* __restrict__ dk,
                                            ushort* __restrict__ zT) {
  __shared__ ushort xa[32 * 64];   // 4KB, byte layout row*128 + (k*2 ^ ((row&7)<<4))
  const int b = blockIdx.x;
  const int t = threadIdx.x;
  const int lane = t & 63, wid = t >> 6;
  const int mg = wid >> 2, ng = wid & 3;
  const int rl = lane & 15, kg = lane >> 4;
  const int srow = t >> 4, sseg = t & 15;
  const int jrow = ((b >> 3) << 8) + ((b & 1) << 7) + ((b >> 1) & 3) + srow * 4;
  const float4* xsrc = (const float4*)(x + (size_t)jrow * 512) + sseg;
  const int swb = (sseg * 8) ^ ((srow & 7) << 4);
  const int arow = mg * 16 + rl;
  float4 xv[8];
#pragma unroll
  for (int kc2 = 0; kc2 < 8; kc2++) xv[kc2] = xsrc[kc2 * 16];   // whole slice upfront

  f32x4 acc[4];
#pragma unroll
  for (int q = 0; q < 4; q++) acc[q] = (f32x4){0.f, 0.f, 0.f, 0.f};

  for (int kc2 = 0; kc2 < 8; kc2++) {
    __syncthreads();
    uint2 pk; pk.x = pack2(xv[kc2].x, xv[kc2].y); pk.y = pack2(xv[kc2].z, xv[kc2].w);
    *(uint2*)((char*)xa + srow * 128 + swb) = pk;
    __syncthreads();
#pragma unroll
    for (int ks = 0; ks < 2; ks++) {
      union { uint4 u; s16x8 s; } av;
      av.u = *(uint4*)((char*)xa + arow * 128 + ((ks * 64 + kg * 16) ^ ((rl & 7) << 4)));
#pragma unroll
      for (int q = 0; q < 4; q++) {
        int n = ng * 64 + q * 16 + rl;
        union { uint4 u; s16x8 s; } bv;
        bv.u = *(const uint4*)(wT + (size_t)n * 512 + kc2 * 64 + ks * 32 + kg * 8);
        acc[q] = __builtin_amdgcn_mfma_f32_16x16x32_bf16(av.s, bv.s, acc[q], 0, 0, 0);
      }
    }
  }
  const int kb = b * 32 + mg * 16 + kg * 4;
  float4 dk4 = *(const float4*)(dk + kb);
#pragma unroll
  for (int q = 0; q < 4; q++) {
    int n = ng * 64 + q * 16 + rl;
    uint2 p;
    p.x = pack2(acc[q][0] * dk4.x, acc[q][1] * dk4.y);
    p.y = pack2(acc[q][2] * dk4.z, acc[q][3] * dk4.w);
    *(uint2*)(zT + (size_t)n * 8192 + kb) = p;
  }
}

// ---------------- K3: part[kc][n][m] = (binA[:,kc] @ z[kc])^T, bf16 ----------
// grid 256 = 32 mb x 8 kc. 8 waves (4 mg x 2 ng), wave 64m x 128n, K-chunk 1024.
__global__ __launch_bounds__(512) void k_spmm(const uint* __restrict__ bits,
                                              const ushort* __restrict__ zT,
                                              ushort* __restrict__ part) {
  __shared__ uint blds[256 * 32];  // 32KB, XOR-swizzled
  const int bx = blockIdx.x;
  const int kc = bx & 7, mb = bx >> 3;
  const int m0 = mb * 256;
  const int t = threadIdx.x;
  const int lane = t & 63, wid = t >> 6;
  const int mg = wid >> 1, ng = wid & 1;
  const int rl = lane & 15, kg = lane >> 4;
  {
    const int row = t >> 1, half = t & 1;
    const uint4* src = (const uint4*)(bits + (size_t)(m0 + row) * 256 + kc * 32 + half * 16);
    uint4 a = src[0], bq = src[1], c = src[2], d = src[3];
    uint vals[16] = {a.x, a.y, a.z, a.w, bq.x, bq.y, bq.z, bq.w,
                     c.x, c.y, c.z, c.w, d.x, d.y, d.z, d.w};
    const int xr = (row & 15) * 2;
#pragma unroll
    for (int i = 0; i < 16; i++)
      blds[row * 32 + ((half * 16 + i) ^ xr)] = vals[i];
  }
  const ushort* zsrc[8];
#pragma unroll
  for (int q = 0; q < 8; q++)
    zsrc[q] = zT + (size_t)(ng * 128 + q * 16 + rl) * 8192 + kc * 1024 + kg * 8;
  __syncthreads();

  uint4 bcur[8], bnxt[8];
#pragma unroll
  for (int q = 0; q < 8; q++) bcur[q] = *(const uint4*)zsrc[q];

  f32x4 acc[4][8];
#pragma unroll
  for (int f = 0; f < 4; f++)
#pragma unroll
    for (int q = 0; q < 8; q++) acc[f][q] = (f32x4){0.f, 0.f, 0.f, 0.f};

  int arow[4];
#pragma unroll
  for (int f = 0; f < 4; f++) arow[f] = (mg * 64 + f * 16 + rl) * 32;
  const int axor = rl * 2;
  const uint shft = kg * 8;

  for (int ks = 0; ks < 32; ks++) {
    if (ks < 31) {
#pragma unroll
      for (int q = 0; q < 8; q++) bnxt[q] = *(const uint4*)(zsrc[q] + (ks + 1) * 32);
    }
    uint aw[4];
#pragma unroll
    for (int f = 0; f < 4; f++) aw[f] = blds[arow[f] + (ks ^ axor)];
#pragma unroll
    for (int f = 0; f < 4; f++) {
      uint byt = (aw[f] >> shft) & 0xFFu;
      union { uint4 u; s16x8 s; } au;
      au.u.x = ((byt * 0x8001u) & 0x10001u) * 0x3F80u;
      au.u.y = (((byt >> 2) * 0x8001u) & 0x10001u) * 0x3F80u;
      au.u.z = (((byt >> 4) * 0x8001u) & 0x10001u) * 0x3F80u;
      au.u.w = (((byt >> 6) * 0x8001u) & 0x10001u) * 0x3F80u;
#pragma unroll
      for (int q = 0; q < 8; q++) {
        union { uint4 u; s16x8 s; } bu; bu.u = bcur[q];
        acc[f][q] = __builtin_amdgcn_mfma_f32_16x16x32_bf16(au.s, bu.s, acc[f][q], 0, 0, 0);
      }
    }
#pragma unroll
    for (int q = 0; q < 8; q++) bcur[q] = bnxt[q];
  }
  ushort* pbase = part + (size_t)kc * 2097152;
#pragma unroll
  for (int f = 0; f < 4; f++)
#pragma unroll
    for (int q = 0; q < 8; q++) {
      int n = ng * 128 + q * 16 + rl;
      int mm = m0 + mg * 64 + f * 16 + kg * 4;
      uint2 p;
      p.x = pack2(acc[f][q][0], acc[f][q][1]);
      p.y = pack2(acc[f][q][2], acc[f][q][3]);
      *(uint2*)(pbase + (size_t)n * 8192 + mm) = p;
    }
}

// ---------------- K4: h = relu(d_m*(sum part + z_self)); out = h @ lwb^T + lb -
__global__ __launch_bounds__(512) void k_lin(const ushort* __restrict__ part,
                                             const ushort* __restrict__ zT,
                                             const float* __restrict__ dinv,
                                             const ushort* __restrict__ lwb,
                                             const float* __restrict__ lb,
                                             float* __restrict__ out) {
  __shared__ ushort hA[32 * 256];  // 16KB, byte layout m*512 + (n*2 ^ ((m&7)<<4))
  __shared__ float sdinv[32];
  const int m0 = blockIdx.x * 32;
  const int t = threadIdx.x;
  if (t < 32) sdinv[t] = dinv[m0 + t];
  {
    const int n = t >> 1, mh = t & 1;
    float sum[16];
#pragma unroll
    for (int j = 0; j < 16; ++j)   // self-loop: gather z at permuted k
      sum[j] = bf2f(zT[(size_t)n * 8192 + kappa(m0 + mh * 16 + j)]);
#pragma unroll
    for (int kcp = 0; kcp < 8; kcp++) {
      const ushort* pp = part + (size_t)kcp * 2097152 + (size_t)n * 8192 + m0 + mh * 16;
      uint4 pa = *(const uint4*)pp, pb = *(const uint4*)(pp + 8);
      uint pu[8] = {pa.x, pa.y, pa.z, pa.w, pb.x, pb.y, pb.z, pb.w};
#pragma unroll
      for (int i = 0; i < 8; i++) {
        sum[2 * i]     += bf2f((ushort)(pu[i] & 0xFFFF));
        sum[2 * i + 1] += bf2f((ushort)(pu[i] >> 16));
      }
    }
    __syncthreads();   // sdinv visible
#pragma unroll
    for (int j = 0; j < 16; j++) {
      int m = mh * 16 + j;
      float h = sum[j] * sdinv[m];
      h = h > 0.f ? h : 0.f;
      *(ushort*)((char*)hA + m * 512 + ((n * 2) ^ ((m & 7) << 4))) = f2bf(h);
    }
  }
  __syncthreads();
  const int lane = t & 63, wid = t >> 6;
  const int rl = lane & 15, kg = lane >> 4;
  f32x4 acc[2][2];
#pragma unroll
  for (int f = 0; f < 2; f++)
#pragma unroll
    for (int q = 0; q < 2; q++) acc[f][q] = (f32x4){0.f, 0.f, 0.f, 0.f};

#pragma unroll
  for (int ks = 0; ks < 8; ks++) {
    union { uint4 u; s16x8 s; } av[2];
#pragma unroll
    for (int f = 0; f < 2; f++)
      av[f].u = *(uint4*)((char*)hA + (f * 16 + rl) * 512 + ((ks * 64 + kg * 16) ^ ((rl & 7) << 4)));
#pragma unroll
    for (int q = 0; q < 2; q++) {
      int no = wid * 32 + q * 16 + rl;
      union { uint4 u; s16x8 s; } bv;
      bv.u = *(const uint4*)(lwb + (size_t)no * 256 + ks * 32 + kg * 8);
#pragma unroll
      for (int f = 0; f < 2; f++)
        acc[f][q] = __builtin_amdgcn_mfma_f32_16x16x32_bf16(av[f].s, bv.s, acc[f][q], 0, 0, 0);
    }
  }
#pragma unroll
  for (int q = 0; q < 2; q++) {
    int no = wid * 32 + q * 16 + rl;
    float bb = lb[no];
#pragma unroll
    for (int f = 0; f < 2; f++) {
      int mbase = m0 + f * 16 + kg * 4;
#pragma unroll
      for (int r = 0; r < 4; r++)
        out[(size_t)(mbase + r) * 256 + no] = acc[f][q][r] + bb;
    }
  }
}

extern "C" void kernel_launch(void* const* d_in, const int* in_sizes, int n_in,
                              void* d_out, int out_size, void* d_ws, size_t ws_size,
                              hipStream_t stream) {
  const float* x   = (const float*)d_in[0];
  const float* adj = (const float*)d_in[1];
  const float* w   = (const float*)d_in[2];
  const float* lw  = (const float*)d_in[3];
  const float* lb  = (const float*)d_in[4];
  float* out = (float*)d_out;

  char* ws = (char*)d_ws;
  float*  dinv = (float*)(ws + 0);                 // 32 KB  [8192]
  float*  dk   = (float*)(ws + (32u << 10));       // 32 KB  [8192] permuted order
  ushort* lwb  = (ushort*)(ws + (128u << 10));     // 128 KB [256 o][256 k] bf16
  ushort* wT   = (ushort*)(ws + (256u << 10));     // 256 KB [256 n][512 k] bf16
  uint*   bits = (uint*)(ws + (1ull << 20));       // 8 MB   [8192 row][256 words]
  ushort* zT   = (ushort*)(ws + (9ull << 20));     // 4 MB   [256 n][8192 k] bf16
  ushort* part = (ushort*)(ws + (16ull << 20));    // 32 MB  [8 kc][256 n][8192 m]

  hipLaunchKernelGGL(k_pack, dim3(2048), dim3(256), 0, stream, adj, w, lw, bits, dinv, dk, wT, lwb);
  hipLaunchKernelGGL(k_xw, dim3(256), dim3(512), 0, stream, x, wT, dk, zT);
  hipLaunchKernelGGL(k_spmm, dim3(256), dim3(512), 0, stream, bits, zT, part);
  hipLaunchKernelGGL(k_lin, dim3(256), dim3(512), 0, stream, part, zT, dinv, lwb, lb, out);
}

// Round 7
// 140.431 us; speedup vs baseline: 1.2103x; 1.2103x over previous
//
#include <hip/hip_runtime.h>
#include <hip/hip_bf16.h>

typedef __attribute__((ext_vector_type(4))) float f32x4;
typedef __attribute__((ext_vector_type(8))) short s16x8;
typedef unsigned int uint;
typedef unsigned short ushort;
typedef unsigned long long u64;

// N=8192, INP=512, OUT=256
// out = relu(D^-1/2 (binA+I) D^-1/2 (x@w)) @ lin_w^T + lin_b
// binA packed via wave ballot (k-axis permuted by kappa); bf16 MFMA GEMMs.
// z kept in MFMA-tiled layout PB: byte((n,k)) = (k>>5)*16384 + (n>>4)*1024
//                                 + ((k>>3)&3)*256 + (n&15)*16 + (k&7)*2

__device__ inline ushort f2bf(float f) {
  union { float f; uint u; } v; v.f = f;
  uint r = (v.u + 0x7FFFu + ((v.u >> 16) & 1u)) >> 16;   // RNE
  return (ushort)r;
}
__device__ inline float bf2f(ushort h) { union { uint u; float f; } v; v.u = ((uint)h) << 16; return v.f; }
__device__ inline uint pack2(float a, float b) { return (uint)f2bf(a) | ((uint)f2bf(b) << 16); }
// ballot packing permutation: column j -> packed k position (ror2 of low byte)
__device__ inline int kappa(int j) {
  return (j & ~255) | ((j & 3) << 6) | (((j >> 7) & 1) << 5) | ((j >> 2) & 31);
}

// ---------------- K1: ballot bit-pack, one row per wave, reg double-buffer ----
__global__ __launch_bounds__(256, 4) void k_pack(const float* __restrict__ adj,
                                                 const float* __restrict__ w,
                                                 const float* __restrict__ lw,
                                                 uint* __restrict__ bits,
                                                 float* __restrict__ dinv,
                                                 float* __restrict__ dk,
                                                 ushort* __restrict__ wT,
                                                 ushort* __restrict__ lwb) {
  const int t = threadIdx.x, lane = t & 63, wv = t >> 6;
  const int b = blockIdx.x;
  const int row = b * 4 + wv;
  const float4* src = (const float4*)(adj + (size_t)row * 8192) + lane;
  uint* dst = bits + (size_t)row * 256;
  float4 cur[4], nxt[4];
#pragma unroll
  for (int j = 0; j < 4; ++j) cur[j] = src[j * 64];
  int cnt = 0;
  for (int bt = 0; bt < 8; ++bt) {
    if (bt < 7) {
#pragma unroll
      for (int j = 0; j < 4; ++j) nxt[j] = src[(bt + 1) * 256 + j * 64];
    }
#pragma unroll
    for (int j = 0; j < 4; ++j) {
      u64 b0 = __ballot(cur[j].x > 0.5f), b1 = __ballot(cur[j].y > 0.5f);
      u64 b2 = __ballot(cur[j].z > 0.5f), b3 = __ballot(cur[j].w > 0.5f);
      cnt += __popcll(b0) + __popcll(b1) + __popcll(b2) + __popcll(b3);
      if (lane == 0) {
        uint4* d4 = (uint4*)(dst + (bt * 4 + j) * 8);
        d4[0] = make_uint4((uint)b0, (uint)(b0 >> 32), (uint)b1, (uint)(b1 >> 32));
        d4[1] = make_uint4((uint)b2, (uint)(b2 >> 32), (uint)b3, (uint)(b3 >> 32));
      }
    }
#pragma unroll
    for (int j = 0; j < 4; ++j) cur[j] = nxt[j];
  }
  if (lane == 0) {
    float d = rsqrtf((float)(cnt + 1));
    dinv[row] = d;
    dk[kappa(row)] = d;
  }
  if (b < 16) {
#pragma unroll
    for (int kk = 0; kk < 32; ++kk) {
      int k = b * 32 + kk;
      wT[(size_t)t * 512 + k] = f2bf(w[(size_t)k * 256 + t]);
    }
  } else if (b < 24) {
    const int b2 = b - 16;
    const float4* s = (const float4*)lw + b2 * 2048;
    uint2* d = (uint2*)lwb + b2 * 2048;
#pragma unroll
    for (int ii = 0; ii < 8; ++ii) {
      float4 v = s[ii * 256 + t];
      uint2 p; p.x = pack2(v.x, v.y); p.y = pack2(v.z, v.w);
      d[ii * 256 + t] = p;
    }
  }
}

// ---------------- K2: PB = tiled( dk[k]*(x@w)[j(k)][n] ), bf16 MFMA -----------
// grid 256; block b handles k-tile bp=(b&7)*32+(b>>3) so PB chunk (bp>>5)==b&7
// is produced on XCD b&7 (matches k_spmm's consumer kc = bx&7).
__global__ __launch_bounds__(512) void k_xw(const float* __restrict__ x,
                                            const ushort* __restrict__ wT,
                                            const float* __restrict__ dk,
                                            ushort* __restrict__ PB) {
  __shared__ ushort xa[32 * 64];   // 4KB, byte layout row*128 + (k*2 ^ ((row&7)<<4))
  const int b = blockIdx.x;
  const int bp = (b & 7) * 32 + (b >> 3);
  const int t = threadIdx.x;
  const int lane = t & 63, wid = t >> 6;
  const int mg = wid >> 2, ng = wid & 3;
  const int rl = lane & 15, kg = lane >> 4;
  const int srow = t >> 4, sseg = t & 15;
  const int jrow = ((bp >> 3) << 8) + ((bp & 1) << 7) + ((bp >> 1) & 3) + srow * 4;
  const float4* xsrc = (const float4*)(x + (size_t)jrow * 512) + sseg;
  const int swb = (sseg * 8) ^ ((srow & 7) << 4);
  const int arow = mg * 16 + rl;
  float4 xv[8];
#pragma unroll
  for (int kc2 = 0; kc2 < 8; kc2++) xv[kc2] = xsrc[kc2 * 16];

  f32x4 acc[4];
#pragma unroll
  for (int q = 0; q < 4; q++) acc[q] = (f32x4){0.f, 0.f, 0.f, 0.f};

  for (int kc2 = 0; kc2 < 8; kc2++) {
    __syncthreads();
    uint2 pk; pk.x = pack2(xv[kc2].x, xv[kc2].y); pk.y = pack2(xv[kc2].z, xv[kc2].w);
    *(uint2*)((char*)xa + srow * 128 + swb) = pk;
    __syncthreads();
#pragma unroll
    for (int ks = 0; ks < 2; ks++) {
      union { uint4 u; s16x8 s; } av;
      av.u = *(uint4*)((char*)xa + arow * 128 + ((ks * 64 + kg * 16) ^ ((rl & 7) << 4)));
#pragma unroll
      for (int q = 0; q < 4; q++) {
        int n = ng * 64 + q * 16 + rl;
        union { uint4 u; s16x8 s; } bv;
        bv.u = *(const uint4*)(wT + (size_t)n * 512 + kc2 * 64 + ks * 32 + kg * 8);
        acc[q] = __builtin_amdgcn_mfma_f32_16x16x32_bf16(av.s, bv.s, acc[q], 0, 0, 0);
      }
    }
  }
  const int kb = bp * 32 + mg * 16 + kg * 4;
  float4 dk4 = *(const float4*)(dk + kb);
  // PB store: slot (q,r) -> byte bp*16384 + (ng*4+q)*1024 + (mg*2+(kg>>1))*256
  //                         + rl*16 + (kg&1)*8 + r*2
  char* pb0 = (char*)PB + (size_t)bp * 16384 + (mg * 2 + (kg >> 1)) * 256 + rl * 16 + (kg & 1) * 8;
#pragma unroll
  for (int q = 0; q < 4; q++) {
    uint2 p;
    p.x = pack2(acc[q][0] * dk4.x, acc[q][1] * dk4.y);
    p.y = pack2(acc[q][2] * dk4.z, acc[q][3] * dk4.w);
    *(uint2*)(pb0 + (ng * 4 + q) * 1024) = p;
  }
}

// ---------------- K3: part[kc][n][m] = (binA[:,kc] @ z[kc])^T, bf16 ----------
// grid 256 = 32 mb x 8 kc (kc=bx&7: XCD-local PB chunk). 8 waves = 2mg x 4ng,
// wave 128m x 64n. A bits: granule-swizzled b128 LDS reads. B: coalesced 1KB loads.
__global__ __launch_bounds__(512) void k_spmm(const uint* __restrict__ bits,
                                              const ushort* __restrict__ PB,
                                              ushort* __restrict__ part) {
  __shared__ uint4 blds4[256 * 8];   // 32 KB: blds4[r*8 + (g^(r&7))] = words 4g..4g+3
  const int bx = blockIdx.x;
  const int kc = bx & 7, mb = bx >> 3;
  const int m0 = mb * 256;
  const int t = threadIdx.x;
  const int lane = t & 63, wid = t >> 6;
  const int mg = wid >> 2, ng = wid & 3;
  const int rl = lane & 15, kg = lane >> 4;
  {
    const int r = t >> 1, h = t & 1;
    const uint4* src = (const uint4*)(bits + (size_t)(m0 + r) * 256 + kc * 32 + h * 16);
#pragma unroll
    for (int i = 0; i < 4; ++i)
      blds4[r * 8 + ((h * 4 + i) ^ (r & 7))] = src[i];
  }
  const char* zb0 = (const char*)PB + (size_t)kc * 32 * 16384 + ng * 4096 + kg * 256 + rl * 16;
  __syncthreads();

  uint4 bcur[4], bnxt[4];
#pragma unroll
  for (int q = 0; q < 4; ++q) bcur[q] = *(const uint4*)(zb0 + q * 1024);

  f32x4 acc[8][4];
#pragma unroll
  for (int f = 0; f < 8; ++f)
#pragma unroll
    for (int q = 0; q < 4; ++q) acc[f][q] = (f32x4){0.f, 0.f, 0.f, 0.f};

  int abase[8];
#pragma unroll
  for (int f = 0; f < 8; ++f) abase[f] = (mg * 128 + f * 16 + rl) * 8;
  const int axor = rl & 7;
  const uint shft = kg * 8;

  for (int a = 0; a < 8; ++a) {
    uint4 aw[8];
#pragma unroll
    for (int f = 0; f < 8; ++f) aw[f] = blds4[abase[f] + (a ^ axor)];
#pragma unroll
    for (int s = 0; s < 4; ++s) {
      const int ks = a * 4 + s;
      if (ks < 31) {
#pragma unroll
        for (int q = 0; q < 4; ++q)
          bnxt[q] = *(const uint4*)(zb0 + (size_t)(ks + 1) * 16384 + q * 1024);
      }
#pragma unroll
      for (int f = 0; f < 8; ++f) {
        uint wrd = (s == 0) ? aw[f].x : (s == 1) ? aw[f].y : (s == 2) ? aw[f].z : aw[f].w;
        uint byt = (wrd >> shft) & 0xFFu;
        union { uint4 u; s16x8 s8; } au;
        au.u.x = ((byt * 0x8001u) & 0x10001u) * 0x3F80u;
        au.u.y = (((byt >> 2) * 0x8001u) & 0x10001u) * 0x3F80u;
        au.u.z = (((byt >> 4) * 0x8001u) & 0x10001u) * 0x3F80u;
        au.u.w = (((byt >> 6) * 0x8001u) & 0x10001u) * 0x3F80u;
#pragma unroll
        for (int q = 0; q < 4; ++q) {
          union { uint4 u; s16x8 s8; } bu; bu.u = bcur[q];
          acc[f][q] = __builtin_amdgcn_mfma_f32_16x16x32_bf16(au.s8, bu.s8, acc[f][q], 0, 0, 0);
        }
      }
#pragma unroll
      for (int q = 0; q < 4; ++q) bcur[q] = bnxt[q];
    }
  }
  ushort* pb = part + ((size_t)kc << 21);
#pragma unroll
  for (int f = 0; f < 8; ++f)
#pragma unroll
    for (int q = 0; q < 4; ++q) {
      int n = ng * 64 + q * 16 + rl;
      int mm = m0 + mg * 128 + f * 16 + kg * 4;
      uint2 p;
      p.x = pack2(acc[f][q][0], acc[f][q][1]);
      p.y = pack2(acc[f][q][2], acc[f][q][3]);
      *(uint2*)(pb + (size_t)n * 8192 + mm) = p;
    }
}

// ---------------- K4: h = relu(d_m*(sum part + z_self)); out = h @ lwb^T + lb -
__global__ __launch_bounds__(512) void k_lin(const ushort* __restrict__ part,
                                             const ushort* __restrict__ PB,
                                             const float* __restrict__ dinv,
                                             const ushort* __restrict__ lwb,
                                             const float* __restrict__ lb,
                                             float* __restrict__ out) {
  __shared__ ushort hA[32 * 256];  // 16KB, byte layout m*512 + (n*2 ^ ((m&7)<<4))
  __shared__ float sdinv[32];
  const int m0 = blockIdx.x * 32;
  const int t = threadIdx.x;
  if (t < 32) sdinv[t] = dinv[m0 + t];
  {
    const int n = t >> 1, mh = t & 1;
    float sum[16];
#pragma unroll
    for (int j = 0; j < 16; ++j) {   // self-loop: gather z at permuted k from PB
      int m = m0 + mh * 16 + j;
      int k = kappa(m);
      size_t byte = (size_t)(k >> 5) * 16384 + (size_t)(n >> 4) * 1024 +
                    ((k >> 3) & 3) * 256 + (n & 15) * 16 + (k & 7) * 2;
      sum[j] = bf2f(*(const ushort*)((const char*)PB + byte));
    }
#pragma unroll
    for (int kcp = 0; kcp < 8; kcp++) {
      const ushort* pp = part + (size_t)kcp * 2097152 + (size_t)n * 8192 + m0 + mh * 16;
      uint4 pa = *(const uint4*)pp, pbq = *(const uint4*)(pp + 8);
      uint pu[8] = {pa.x, pa.y, pa.z, pa.w, pbq.x, pbq.y, pbq.z, pbq.w};
#pragma unroll
      for (int i = 0; i < 8; i++) {
        sum[2 * i]     += bf2f((ushort)(pu[i] & 0xFFFF));
        sum[2 * i + 1] += bf2f((ushort)(pu[i] >> 16));
      }
    }
    __syncthreads();   // sdinv visible
#pragma unroll
    for (int j = 0; j < 16; j++) {
      int m = mh * 16 + j;
      float h = sum[j] * sdinv[m];
      h = h > 0.f ? h : 0.f;
      *(ushort*)((char*)hA + m * 512 + ((n * 2) ^ ((m & 7) << 4))) = f2bf(h);
    }
  }
  __syncthreads();
  const int lane = t & 63, wid = t >> 6;
  const int rl = lane & 15, kg = lane >> 4;
  f32x4 acc[2][2];
#pragma unroll
  for (int f = 0; f < 2; f++)
#pragma unroll
    for (int q = 0; q < 2; q++) acc[f][q] = (f32x4){0.f, 0.f, 0.f, 0.f};

#pragma unroll
  for (int ks = 0; ks < 8; ks++) {
    union { uint4 u; s16x8 s; } av[2];
#pragma unroll
    for (int f = 0; f < 2; f++)
      av[f].u = *(uint4*)((char*)hA + (f * 16 + rl) * 512 + ((ks * 64 + kg * 16) ^ ((rl & 7) << 4)));
#pragma unroll
    for (int q = 0; q < 2; q++) {
      int no = wid * 32 + q * 16 + rl;
      union { uint4 u; s16x8 s; } bv;
      bv.u = *(const uint4*)(lwb + (size_t)no * 256 + ks * 32 + kg * 8);
#pragma unroll
      for (int f = 0; f < 2; f++)
        acc[f][q] = __builtin_amdgcn_mfma_f32_16x16x32_bf16(av[f].s, bv.s, acc[f][q], 0, 0, 0);
    }
  }
#pragma unroll
  for (int q = 0; q < 2; q++) {
    int no = wid * 32 + q * 16 + rl;
    float bb = lb[no];
#pragma unroll
    for (int f = 0; f < 2; f++) {
      int mbase = m0 + f * 16 + kg * 4;
#pragma unroll
      for (int r = 0; r < 4; r++)
        out[(size_t)(mbase + r) * 256 + no] = acc[f][q][r] + bb;
    }
  }
}

extern "C" void kernel_launch(void* const* d_in, const int* in_sizes, int n_in,
                              void* d_out, int out_size, void* d_ws, size_t ws_size,
                              hipStream_t stream) {
  const float* x   = (const float*)d_in[0];
  const float* adj = (const float*)d_in[1];
  const float* w   = (const float*)d_in[2];
  const float* lw  = (const float*)d_in[3];
  const float* lb  = (const float*)d_in[4];
  float* out = (float*)d_out;

  char* ws = (char*)d_ws;
  float*  dinv = (float*)(ws + 0);                 // 32 KB  [8192]
  float*  dk   = (float*)(ws + (32u << 10));       // 32 KB  [8192] permuted order
  ushort* lwb  = (ushort*)(ws + (128u << 10));     // 128 KB [256 o][256 k] bf16
  ushort* wT   = (ushort*)(ws + (256u << 10));     // 256 KB [256 n][512 k] bf16
  uint*   bits = (uint*)(ws + (1ull << 20));       // 8 MB   [8192 row][256 words]
  ushort* PB   = (ushort*)(ws + (9ull << 20));     // 4 MB   tiled z (see header)
  ushort* part = (ushort*)(ws + (16ull << 20));    // 32 MB  [8 kc][256 n][8192 m]

  hipLaunchKernelGGL(k_pack, dim3(2048), dim3(256), 0, stream, adj, w, lw, bits, dinv, dk, wT, lwb);
  hipLaunchKernelGGL(k_xw, dim3(256), dim3(512), 0, stream, x, wT, dk, PB);
  hipLaunchKernelGGL(k_spmm, dim3(256), dim3(512), 0, stream, bits, PB, part);
  hipLaunchKernelGGL(k_lin, dim3(256), dim3(512), 0, stream, part, PB, dinv, lwb, lb, out);
}